// Round 1
// baseline (1305.134 us; speedup 1.0000x reference)
//
#include <hip/hip_runtime.h>
#include <hip/hip_bf16.h>
#include <stdint.h>

#define N_NODES 10000
#define N_EDGES 160000
#define FEAT    256
#define NRELS   16
#define BM      64
#define MAX_TILES (N_EDGES / BM + NRELS)   // 2516

typedef __attribute__((ext_vector_type(8))) short bf16x8;
typedef __attribute__((ext_vector_type(4))) float f32x4;

struct Tile { int rel; int row0; int cnt; };

__device__ __forceinline__ unsigned short f2bf(float f) {
    union { float f; unsigned u; } v; v.f = f;
    unsigned u = v.u;
    u += 0x7FFFu + ((u >> 16) & 1u);   // round-to-nearest-even
    return (unsigned short)(u >> 16);
}

// ---- prep: fp32 -> bf16 (vectorized), feat stays [N][256] ----
__global__ __launch_bounds__(256) void k_f2bf4(const float4* __restrict__ src,
                                               ushort4* __restrict__ dst, int n4) {
    int i = blockIdx.x * 256 + threadIdx.x;
    if (i < n4) {
        float4 v = src[i];
        ushort4 r;
        r.x = f2bf(v.x); r.y = f2bf(v.y); r.z = f2bf(v.z); r.w = f2bf(v.w);
        dst[i] = r;
    }
}

// ---- prep: W [R][I][O] fp32 -> Wt [R][O][I] bf16 (coalesced writes) ----
__global__ __launch_bounds__(256) void k_wt(const float* __restrict__ w,
                                            unsigned short* __restrict__ wt, int total) {
    int idx = blockIdx.x * 256 + threadIdx.x;
    if (idx < total) {
        int i = idx & 255;
        int o = (idx >> 8) & 255;
        int r = idx >> 16;
        wt[idx] = f2bf(w[((r << 8) + i) * 256 + o]);
    }
}

// ---- degrees + relation counts ----
__global__ __launch_bounds__(256) void k_deg(const int* __restrict__ src,
                                             const int* __restrict__ dst,
                                             const int* __restrict__ et,
                                             float* degd, float* degs, int* counts) {
    int e = blockIdx.x * 256 + threadIdx.x;
    if (e < N_EDGES) {
        atomicAdd(&degd[dst[e]], 1.0f);
        atomicAdd(&degs[src[e]], 1.0f);
        atomicAdd(&counts[et[e]], 1);
    }
}

// ---- degree -> inverse (0 if zero-degree) ----
__global__ __launch_bounds__(256) void k_norm(float* degd, float* degs) {
    int i = blockIdx.x * 256 + threadIdx.x;
    if (i < N_NODES) {
        float d = degd[i]; degd[i] = d > 0.f ? 1.f / d : 0.f;
        float s = degs[i]; degs[i] = s > 0.f ? 1.f / s : 0.f;
    }
}

// ---- scan counts, init cursors, build tile descriptors ----
__global__ __launch_bounds__(256) void k_desc(const int* __restrict__ counts,
                                              int* cursors, Tile* tiles) {
    __shared__ int off[NRELS + 1];
    __shared__ int toff[NRELS + 1];
    if (threadIdx.x == 0) {
        int a = 0, t = 0;
        for (int r = 0; r < NRELS; r++) {
            off[r] = a; toff[r] = t;
            a += counts[r];
            t += (counts[r] + BM - 1) / BM;
        }
        off[NRELS] = a; toff[NRELS] = t;
    }
    __syncthreads();
    if (threadIdx.x < NRELS) cursors[threadIdx.x] = off[threadIdx.x];
    for (int t = threadIdx.x; t < MAX_TILES; t += 256) {
        Tile tl; tl.rel = 0; tl.row0 = 0; tl.cnt = 0;
        for (int r = 0; r < NRELS; r++) {
            if (t >= toff[r] && t < toff[r + 1]) {
                int k = t - toff[r];
                tl.rel = r;
                tl.row0 = off[r] + k * BM;
                int rem = counts[r] - k * BM;
                tl.cnt = rem < BM ? rem : BM;
            }
        }
        tiles[t] = tl;
    }
}

// ---- bucket-fill: edge ids grouped by relation ----
__global__ __launch_bounds__(256) void k_fill(const int* __restrict__ et,
                                              int* cursors, int* perm) {
    int e = blockIdx.x * 256 + threadIdx.x;
    if (e < N_EDGES) {
        int p = atomicAdd(&cursors[et[e]], 1);
        perm[p] = e;
    }
}

// ---- self loop: out = 2*(feat @ loop_weight) + self_bias  (overwrites out) ----
__global__ __launch_bounds__(256) void k_self(const unsigned short* __restrict__ featb,
                                              const unsigned short* __restrict__ lwt,
                                              const float* __restrict__ sbias,
                                              float* __restrict__ out) {
    int m0 = blockIdx.x * BM;
    int wave = threadIdx.x >> 6, lane = threadIdx.x & 63;
    int nb = wave * 64, lr = lane & 15, lg = lane >> 4;
    f32x4 acc[4][4] = {};
    for (int k0 = 0; k0 < FEAT; k0 += 32) {
        int kk = k0 + lg * 8;
        bf16x8 a[4], b[4];
        for (int mi = 0; mi < 4; mi++) {
            int row = m0 + mi * 16 + lr;
            if (row >= N_NODES) row = N_NODES - 1;   // masked at store
            a[mi] = *(const bf16x8*)(featb + row * FEAT + kk);
        }
        for (int ni = 0; ni < 4; ni++) {
            int col = nb + ni * 16 + lr;
            b[ni] = *(const bf16x8*)(lwt + col * FEAT + kk);
        }
        for (int mi = 0; mi < 4; mi++)
            for (int ni = 0; ni < 4; ni++)
                acc[mi][ni] = __builtin_amdgcn_mfma_f32_16x16x32_bf16(a[mi], b[ni], acc[mi][ni], 0, 0, 0);
    }
    for (int mi = 0; mi < 4; mi++) {
        for (int j = 0; j < 4; j++) {
            int row = m0 + mi * 16 + lg * 4 + j;
            if (row < N_NODES) {
                for (int ni = 0; ni < 4; ni++) {
                    int col = nb + ni * 16 + lr;
                    out[row * FEAT + col] = 2.0f * acc[mi][ni][j] + sbias[col];
                }
            }
        }
    }
}

// ---- fused edge pass: gather feat[gidx] rows, GEMM vs W[rel], scale, scatter ----
__global__ __launch_bounds__(256) void k_edge(const unsigned short* __restrict__ featb,
                                              const unsigned short* __restrict__ wt,
                                              const float* __restrict__ bias,
                                              const float* __restrict__ normv,
                                              const int* __restrict__ gidx,
                                              const int* __restrict__ sidx,
                                              const int* __restrict__ perm,
                                              const Tile* __restrict__ tiles,
                                              float* __restrict__ out) {
    Tile tl = tiles[blockIdx.x];
    if (tl.cnt == 0) return;
    int wave = threadIdx.x >> 6, lane = threadIdx.x & 63;
    int nb = wave * 64, lr = lane & 15, lg = lane >> 4;
    const unsigned short* wr = wt + tl.rel * FEAT * FEAT;

    int anode[4];
    for (int mi = 0; mi < 4; mi++) {
        int row = mi * 16 + lr;
        int eid = (row < tl.cnt) ? perm[tl.row0 + row] : perm[tl.row0];
        anode[mi] = gidx[eid];
    }

    f32x4 acc[4][4] = {};
    for (int k0 = 0; k0 < FEAT; k0 += 32) {
        int kk = k0 + lg * 8;
        bf16x8 a[4], b[4];
        for (int mi = 0; mi < 4; mi++)
            a[mi] = *(const bf16x8*)(featb + anode[mi] * FEAT + kk);
        for (int ni = 0; ni < 4; ni++)
            b[ni] = *(const bf16x8*)(wr + (nb + ni * 16 + lr) * FEAT + kk);
        for (int mi = 0; mi < 4; mi++)
            for (int ni = 0; ni < 4; ni++)
                acc[mi][ni] = __builtin_amdgcn_mfma_f32_16x16x32_bf16(a[mi], b[ni], acc[mi][ni], 0, 0, 0);
    }

    float bv[4];
    for (int ni = 0; ni < 4; ni++) bv[ni] = bias[nb + ni * 16 + lr];

    for (int mi = 0; mi < 4; mi++) {
        for (int j = 0; j < 4; j++) {
            int row = mi * 16 + lg * 4 + j;
            if (row < tl.cnt) {
                int eid = perm[tl.row0 + row];
                int dn = sidx[eid];
                float nrm = normv[dn];
                float* op = out + dn * FEAT + nb + lr;
                for (int ni = 0; ni < 4; ni++)
                    atomicAdd(op + ni * 16, (acc[mi][ni][j] + bv[ni]) * nrm);
            }
        }
    }
}

extern "C" void kernel_launch(void* const* d_in, const int* in_sizes, int n_in,
                              void* d_out, int out_size, void* d_ws, size_t ws_size,
                              hipStream_t stream) {
    const float* feat  = (const float*)d_in[0];
    const float* Wf    = (const float*)d_in[1];
    const float* Wb    = (const float*)d_in[2];
    const float* lw    = (const float*)d_in[3];
    const float* fbias = (const float*)d_in[4];
    const float* bbias = (const float*)d_in[5];
    const float* sbias = (const float*)d_in[6];
    const int*   src   = (const int*)d_in[7];
    const int*   dst   = (const int*)d_in[8];
    const int*   et    = (const int*)d_in[9];
    float* out = (float*)d_out;

    char* ws = (char*)d_ws;
    size_t off = 0;
    int*   counts  = (int*)(ws + off);   off += 64;
    int*   cursors = (int*)(ws + off);   off += 64;
    float* degd    = (float*)(ws + off); off += N_NODES * 4;          // -> norm_dst
    size_t degs_off = (off + 255) & ~(size_t)255;
    float* degs    = (float*)(ws + degs_off); off = degs_off + N_NODES * 4;  // -> norm_src
    size_t zero_bytes = off;                                          // memset prefix
    off = (off + 255) & ~(size_t)255;
    int*   perm    = (int*)(ws + off);   off += N_EDGES * 4;
    off = (off + 255) & ~(size_t)255;
    Tile*  tiles   = (Tile*)(ws + off);  off += MAX_TILES * sizeof(Tile);
    off = (off + 255) & ~(size_t)255;
    unsigned short* featb = (unsigned short*)(ws + off); off += (size_t)N_NODES * FEAT * 2;
    off = (off + 255) & ~(size_t)255;
    unsigned short* wft   = (unsigned short*)(ws + off); off += (size_t)NRELS * FEAT * FEAT * 2;
    off = (off + 255) & ~(size_t)255;
    unsigned short* wbt   = (unsigned short*)(ws + off); off += (size_t)NRELS * FEAT * FEAT * 2;
    off = (off + 255) & ~(size_t)255;
    unsigned short* lwt   = (unsigned short*)(ws + off); off += (size_t)FEAT * FEAT * 2;

    hipMemsetAsync(d_ws, 0, zero_bytes, stream);

    // prep conversions
    {
        int n4 = N_NODES * FEAT / 4;
        k_f2bf4<<<(n4 + 255) / 256, 256, 0, stream>>>((const float4*)feat, (ushort4*)featb, n4);
        int tw = NRELS * FEAT * FEAT;
        k_wt<<<(tw + 255) / 256, 256, 0, stream>>>(Wf, wft, tw);
        k_wt<<<(tw + 255) / 256, 256, 0, stream>>>(Wb, wbt, tw);
        int tl = FEAT * FEAT;
        k_wt<<<(tl + 255) / 256, 256, 0, stream>>>(lw, lwt, tl);
    }

    // degrees + counts, norms, descriptors, bucket fill
    k_deg<<<(N_EDGES + 255) / 256, 256, 0, stream>>>(src, dst, et, degd, degs, counts);
    k_norm<<<(N_NODES + 255) / 256, 256, 0, stream>>>(degd, degs);
    k_desc<<<1, 256, 0, stream>>>(counts, cursors, tiles);
    k_fill<<<(N_EDGES + 255) / 256, 256, 0, stream>>>(et, cursors, perm);

    // self loop (overwrites out), then both edge passes accumulate
    k_self<<<(N_NODES + BM - 1) / BM, 256, 0, stream>>>(featb, lwt, sbias, out);
    // forward: gather feat[src], scatter to dst, norm = 1/indeg_dst(dst)
    k_edge<<<MAX_TILES, 256, 0, stream>>>(featb, wft, fbias, degd, src, dst, perm, tiles, out);
    // backward: gather feat[dst], scatter to src, norm = 1/deg_src(src)
    k_edge<<<MAX_TILES, 256, 0, stream>>>(featb, wbt, bbias, degs, dst, src, perm, tiles, out);
}

// Round 2
// 454.430 us; speedup vs baseline: 2.8720x; 2.8720x over previous
//
#include <hip/hip_runtime.h>
#include <hip/hip_bf16.h>
#include <stdint.h>

#define N_NODES 10000
#define N_EDGES 160000
#define FEAT    256
#define NRELS   16
#define BM      64
#define MAX_TILES (N_EDGES / BM + NRELS)   // 2516

typedef __attribute__((ext_vector_type(8))) short bf16x8;
typedef __attribute__((ext_vector_type(4))) float f32x4;

struct Tile { int rel; int row0; int cnt; };

__device__ __forceinline__ unsigned short f2bf(float f) {
    union { float f; unsigned u; } v; v.f = f;
    unsigned u = v.u;
    u += 0x7FFFu + ((u >> 16) & 1u);   // round-to-nearest-even
    return (unsigned short)(u >> 16);
}

// ---- prep: fp32 -> bf16 (vectorized), feat stays [N][256] ----
__global__ __launch_bounds__(256) void k_f2bf4(const float4* __restrict__ src,
                                               ushort4* __restrict__ dst, int n4) {
    int i = blockIdx.x * 256 + threadIdx.x;
    if (i < n4) {
        float4 v = src[i];
        ushort4 r;
        r.x = f2bf(v.x); r.y = f2bf(v.y); r.z = f2bf(v.z); r.w = f2bf(v.w);
        dst[i] = r;
    }
}

// ---- prep: W [R][I][O] fp32 -> Wt [R][O][I] bf16 (coalesced writes) ----
__global__ __launch_bounds__(256) void k_wt(const float* __restrict__ w,
                                            unsigned short* __restrict__ wt, int total) {
    int idx = blockIdx.x * 256 + threadIdx.x;
    if (idx < total) {
        int i = idx & 255;
        int o = (idx >> 8) & 255;
        int r = idx >> 16;
        wt[idx] = f2bf(w[((r << 8) + i) * 256 + o]);
    }
}

// ---- degrees (int, low contention) + relation counts (LDS histogram) ----
__global__ __launch_bounds__(256) void k_count(const int* __restrict__ src,
                                               const int* __restrict__ dst,
                                               const int* __restrict__ et,
                                               int* degd, int* degs, int* counts) {
    __shared__ int lc[NRELS];
    if (threadIdx.x < NRELS) lc[threadIdx.x] = 0;
    __syncthreads();
    int e = blockIdx.x * 256 + threadIdx.x;
    if (e < N_EDGES) {
        atomicAdd(&degd[dst[e]], 1);
        atomicAdd(&degs[src[e]], 1);
        atomicAdd(&lc[et[e]], 1);
    }
    __syncthreads();
    if (threadIdx.x < NRELS && lc[threadIdx.x] > 0)
        atomicAdd(&counts[threadIdx.x], lc[threadIdx.x]);
}

// ---- int degree -> float inverse, in place (0 if zero-degree) ----
__global__ __launch_bounds__(256) void k_norm(int* degd, int* degs) {
    int i = blockIdx.x * 256 + threadIdx.x;
    if (i < N_NODES) {
        int d = degd[i];
        ((float*)degd)[i] = d > 0 ? 1.f / (float)d : 0.f;
        int s = degs[i];
        ((float*)degs)[i] = s > 0 ? 1.f / (float)s : 0.f;
    }
}

// ---- scan counts, init cursors, build tile descriptors ----
__global__ __launch_bounds__(256) void k_desc(const int* __restrict__ counts,
                                              int* cursors, Tile* tiles) {
    __shared__ int off[NRELS + 1];
    __shared__ int toff[NRELS + 1];
    if (threadIdx.x == 0) {
        int a = 0, t = 0;
        for (int r = 0; r < NRELS; r++) {
            off[r] = a; toff[r] = t;
            a += counts[r];
            t += (counts[r] + BM - 1) / BM;
        }
        off[NRELS] = a; toff[NRELS] = t;
    }
    __syncthreads();
    if (threadIdx.x < NRELS) cursors[threadIdx.x] = off[threadIdx.x];
    for (int t = threadIdx.x; t < MAX_TILES; t += 256) {
        Tile tl; tl.rel = 0; tl.row0 = 0; tl.cnt = 0;
        for (int r = 0; r < NRELS; r++) {
            if (t >= toff[r] && t < toff[r + 1]) {
                int k = t - toff[r];
                tl.rel = r;
                tl.row0 = off[r] + k * BM;
                int rem = counts[r] - k * BM;
                tl.cnt = rem < BM ? rem : BM;
            }
        }
        tiles[t] = tl;
    }
}

// ---- bucket-fill via LDS ranking: 16 global atomics per block ----
__global__ __launch_bounds__(256) void k_fill(const int* __restrict__ et,
                                              int* cursors, int* perm) {
    __shared__ int lc[NRELS];
    __shared__ int lbase[NRELS];
    if (threadIdx.x < NRELS) lc[threadIdx.x] = 0;
    __syncthreads();
    int e = blockIdx.x * 256 + threadIdx.x;
    int r = -1, rank = 0;
    if (e < N_EDGES) {
        r = et[e];
        rank = atomicAdd(&lc[r], 1);
    }
    __syncthreads();
    if (threadIdx.x < NRELS && lc[threadIdx.x] > 0)
        lbase[threadIdx.x] = atomicAdd(&cursors[threadIdx.x], lc[threadIdx.x]);
    __syncthreads();
    if (e < N_EDGES)
        perm[lbase[r] + rank] = e;
}

// ---- self loop: out = 2*(feat @ loop_weight) + self_bias  (overwrites out) ----
__global__ __launch_bounds__(256) void k_self(const unsigned short* __restrict__ featb,
                                              const unsigned short* __restrict__ lwt,
                                              const float* __restrict__ sbias,
                                              float* __restrict__ out) {
    int m0 = blockIdx.x * BM;
    int wave = threadIdx.x >> 6, lane = threadIdx.x & 63;
    int nb = wave * 64, lr = lane & 15, lg = lane >> 4;
    f32x4 acc[4][4] = {};
    for (int k0 = 0; k0 < FEAT; k0 += 32) {
        int kk = k0 + lg * 8;
        bf16x8 a[4], b[4];
        for (int mi = 0; mi < 4; mi++) {
            int row = m0 + mi * 16 + lr;
            if (row >= N_NODES) row = N_NODES - 1;   // masked at store
            a[mi] = *(const bf16x8*)(featb + row * FEAT + kk);
        }
        for (int ni = 0; ni < 4; ni++) {
            int col = nb + ni * 16 + lr;
            b[ni] = *(const bf16x8*)(lwt + col * FEAT + kk);
        }
        for (int mi = 0; mi < 4; mi++)
            for (int ni = 0; ni < 4; ni++)
                acc[mi][ni] = __builtin_amdgcn_mfma_f32_16x16x32_bf16(a[mi], b[ni], acc[mi][ni], 0, 0, 0);
    }
    for (int mi = 0; mi < 4; mi++) {
        for (int j = 0; j < 4; j++) {
            int row = m0 + mi * 16 + lg * 4 + j;
            if (row < N_NODES) {
                for (int ni = 0; ni < 4; ni++) {
                    int col = nb + ni * 16 + lr;
                    out[row * FEAT + col] = 2.0f * acc[mi][ni][j] + sbias[col];
                }
            }
        }
    }
}

// ---- fused edge pass: gather feat[gidx] rows, GEMM vs W[rel], scale, scatter ----
__global__ __launch_bounds__(256) void k_edge(const unsigned short* __restrict__ featb,
                                              const unsigned short* __restrict__ wt,
                                              const float* __restrict__ bias,
                                              const float* __restrict__ normv,
                                              const int* __restrict__ gidx,
                                              const int* __restrict__ sidx,
                                              const int* __restrict__ perm,
                                              const Tile* __restrict__ tiles,
                                              float* __restrict__ out) {
    Tile tl = tiles[blockIdx.x];
    if (tl.cnt == 0) return;
    int wave = threadIdx.x >> 6, lane = threadIdx.x & 63;
    int nb = wave * 64, lr = lane & 15, lg = lane >> 4;
    const unsigned short* wr = wt + tl.rel * FEAT * FEAT;

    int anode[4];
    for (int mi = 0; mi < 4; mi++) {
        int row = mi * 16 + lr;
        int eid = (row < tl.cnt) ? perm[tl.row0 + row] : perm[tl.row0];
        anode[mi] = gidx[eid];
    }

    f32x4 acc[4][4] = {};
    for (int k0 = 0; k0 < FEAT; k0 += 32) {
        int kk = k0 + lg * 8;
        bf16x8 a[4], b[4];
        for (int mi = 0; mi < 4; mi++)
            a[mi] = *(const bf16x8*)(featb + anode[mi] * FEAT + kk);
        for (int ni = 0; ni < 4; ni++)
            b[ni] = *(const bf16x8*)(wr + (nb + ni * 16 + lr) * FEAT + kk);
        for (int mi = 0; mi < 4; mi++)
            for (int ni = 0; ni < 4; ni++)
                acc[mi][ni] = __builtin_amdgcn_mfma_f32_16x16x32_bf16(a[mi], b[ni], acc[mi][ni], 0, 0, 0);
    }

    float bv[4];
    for (int ni = 0; ni < 4; ni++) bv[ni] = bias[nb + ni * 16 + lr];

    for (int mi = 0; mi < 4; mi++) {
        for (int j = 0; j < 4; j++) {
            int row = mi * 16 + lg * 4 + j;
            if (row < tl.cnt) {
                int eid = perm[tl.row0 + row];
                int dn = sidx[eid];
                float nrm = normv[dn];
                float* op = out + dn * FEAT + nb + lr;
                for (int ni = 0; ni < 4; ni++)
                    atomicAdd(op + ni * 16, (acc[mi][ni][j] + bv[ni]) * nrm);
            }
        }
    }
}

extern "C" void kernel_launch(void* const* d_in, const int* in_sizes, int n_in,
                              void* d_out, int out_size, void* d_ws, size_t ws_size,
                              hipStream_t stream) {
    const float* feat  = (const float*)d_in[0];
    const float* Wf    = (const float*)d_in[1];
    const float* Wb    = (const float*)d_in[2];
    const float* lw    = (const float*)d_in[3];
    const float* fbias = (const float*)d_in[4];
    const float* bbias = (const float*)d_in[5];
    const float* sbias = (const float*)d_in[6];
    const int*   src   = (const int*)d_in[7];
    const int*   dst   = (const int*)d_in[8];
    const int*   et    = (const int*)d_in[9];
    float* out = (float*)d_out;

    char* ws = (char*)d_ws;
    size_t off = 0;
    int*   counts  = (int*)(ws + off);   off += 64;
    int*   cursors = (int*)(ws + off);   off += 64;
    int*   degd    = (int*)(ws + off);   off += N_NODES * 4;          // -> norm_dst (float, in place)
    size_t degs_off = (off + 255) & ~(size_t)255;
    int*   degs    = (int*)(ws + degs_off); off = degs_off + N_NODES * 4;  // -> norm_src
    size_t zero_bytes = off;                                          // memset prefix
    off = (off + 255) & ~(size_t)255;
    int*   perm    = (int*)(ws + off);   off += N_EDGES * 4;
    off = (off + 255) & ~(size_t)255;
    Tile*  tiles   = (Tile*)(ws + off);  off += MAX_TILES * sizeof(Tile);
    off = (off + 255) & ~(size_t)255;
    unsigned short* featb = (unsigned short*)(ws + off); off += (size_t)N_NODES * FEAT * 2;
    off = (off + 255) & ~(size_t)255;
    unsigned short* wft   = (unsigned short*)(ws + off); off += (size_t)NRELS * FEAT * FEAT * 2;
    off = (off + 255) & ~(size_t)255;
    unsigned short* wbt   = (unsigned short*)(ws + off); off += (size_t)NRELS * FEAT * FEAT * 2;
    off = (off + 255) & ~(size_t)255;
    unsigned short* lwt   = (unsigned short*)(ws + off); off += (size_t)FEAT * FEAT * 2;

    hipMemsetAsync(d_ws, 0, zero_bytes, stream);

    // prep conversions
    {
        int n4 = N_NODES * FEAT / 4;
        k_f2bf4<<<(n4 + 255) / 256, 256, 0, stream>>>((const float4*)feat, (ushort4*)featb, n4);
        int tw = NRELS * FEAT * FEAT;
        k_wt<<<(tw + 255) / 256, 256, 0, stream>>>(Wf, wft, tw);
        k_wt<<<(tw + 255) / 256, 256, 0, stream>>>(Wb, wbt, tw);
        int tl = FEAT * FEAT;
        k_wt<<<(tl + 255) / 256, 256, 0, stream>>>(lw, lwt, tl);
    }

    // degrees + counts, norms, descriptors, bucket fill
    k_count<<<(N_EDGES + 255) / 256, 256, 0, stream>>>(src, dst, et, degd, degs, counts);
    k_norm<<<(N_NODES + 255) / 256, 256, 0, stream>>>(degd, degs);
    k_desc<<<1, 256, 0, stream>>>(counts, cursors, tiles);
    k_fill<<<(N_EDGES + 255) / 256, 256, 0, stream>>>(et, cursors, perm);

    // self loop (overwrites out), then both edge passes accumulate
    k_self<<<(N_NODES + BM - 1) / BM, 256, 0, stream>>>(featb, lwt, sbias, out);
    // forward: gather feat[src], scatter to dst, norm = 1/indeg_dst(dst)
    k_edge<<<MAX_TILES, 256, 0, stream>>>(featb, wft, fbias, (const float*)degd, src, dst, perm, tiles, out);
    // backward: gather feat[dst], scatter to src, norm = 1/deg_src(src)
    k_edge<<<MAX_TILES, 256, 0, stream>>>(featb, wbt, bbias, (const float*)degs, dst, src, perm, tiles, out);
}

// Round 3
// 338.589 us; speedup vs baseline: 3.8546x; 1.3421x over previous
//
#include <hip/hip_runtime.h>
#include <hip/hip_bf16.h>
#include <stdint.h>

#define N_NODES 10000
#define N_EDGES 160000
#define FEAT    256
#define NRELS   16
#define BM      64
#define MAX_TILES (N_EDGES / BM + NRELS)   // 2516

typedef __attribute__((ext_vector_type(8))) short bf16x8;
typedef __attribute__((ext_vector_type(4))) float f32x4;

struct Tile { int rel; int row0; int cnt; };

__device__ __forceinline__ unsigned short f2bf(float f) {
    union { float f; unsigned u; } v; v.f = f;
    unsigned u = v.u;
    u += 0x7FFFu + ((u >> 16) & 1u);   // round-to-nearest-even
    return (unsigned short)(u >> 16);
}
__device__ __forceinline__ float bf2f(unsigned short u) {
    union { unsigned u; float f; } v; v.u = ((unsigned)u) << 16;
    return v.f;
}

// ---- prep: fp32 -> bf16 (vectorized) ----
__global__ __launch_bounds__(256) void k_f2bf4(const float4* __restrict__ src,
                                               ushort4* __restrict__ dst, int n4) {
    int i = blockIdx.x * 256 + threadIdx.x;
    if (i < n4) {
        float4 v = src[i];
        ushort4 r;
        r.x = f2bf(v.x); r.y = f2bf(v.y); r.z = f2bf(v.z); r.w = f2bf(v.w);
        dst[i] = r;
    }
}

// ---- prep: W [R][I][O] fp32 -> Wt [R][O][I] bf16 ----
__global__ __launch_bounds__(256) void k_wt(const float* __restrict__ w,
                                            unsigned short* __restrict__ wt, int total) {
    int idx = blockIdx.x * 256 + threadIdx.x;
    if (idx < total) {
        int i = idx & 255;
        int o = (idx >> 8) & 255;
        int r = idx >> 16;
        wt[idx] = f2bf(w[((r << 8) + i) * 256 + o]);
    }
}

// ---- degrees (int) + relation counts (LDS histogram) ----
__global__ __launch_bounds__(256) void k_count(const int* __restrict__ src,
                                               const int* __restrict__ dst,
                                               const int* __restrict__ et,
                                               int* degd, int* degs, int* counts) {
    __shared__ int lc[NRELS];
    if (threadIdx.x < NRELS) lc[threadIdx.x] = 0;
    __syncthreads();
    int e = blockIdx.x * 256 + threadIdx.x;
    if (e < N_EDGES) {
        atomicAdd(&degd[dst[e]], 1);
        atomicAdd(&degs[src[e]], 1);
        atomicAdd(&lc[et[e]], 1);
    }
    __syncthreads();
    if (threadIdx.x < NRELS && lc[threadIdx.x] > 0)
        atomicAdd(&counts[threadIdx.x], lc[threadIdx.x]);
}

// ---- single-block exclusive scan of both degree arrays; init cursors + norms ----
__global__ __launch_bounds__(1024) void k_scan(const int* __restrict__ degd,
                                               const int* __restrict__ degs,
                                               int* offf, int* offb,
                                               int* curf, int* curb,
                                               float* normf, float* normb) {
    __shared__ int sf[1024], sb[1024];
    int t = threadIdx.x;
    const int CH = (N_NODES + 1023) / 1024;   // 10
    int base = t * CH;
    int sumf = 0, sumb = 0;
    for (int i = 0; i < CH; i++) {
        int n = base + i;
        if (n < N_NODES) { sumf += degd[n]; sumb += degs[n]; }
    }
    sf[t] = sumf; sb[t] = sumb;
    __syncthreads();
    for (int d = 1; d < 1024; d <<= 1) {
        int vf = (t >= d) ? sf[t - d] : 0;
        int vb = (t >= d) ? sb[t - d] : 0;
        __syncthreads();
        sf[t] += vf; sb[t] += vb;
        __syncthreads();
    }
    int runf = t ? sf[t - 1] : 0;
    int runb = t ? sb[t - 1] : 0;
    for (int i = 0; i < CH; i++) {
        int n = base + i;
        if (n < N_NODES) {
            int df = degd[n], db = degs[n];
            offf[n] = runf; offb[n] = runb;
            curf[n] = runf; curb[n] = runb;
            normf[n] = df > 0 ? 1.f / (float)df : 0.f;
            normb[n] = db > 0 ? 1.f / (float)db : 0.f;
            runf += df; runb += db;
        }
    }
    if (t == 1023) { offf[N_NODES] = runf; offb[N_NODES] = runb; }
}

// ---- scan relation counts, init relation cursors, build tile descriptors ----
__global__ __launch_bounds__(256) void k_desc(const int* __restrict__ counts,
                                              int* cursors, Tile* tiles) {
    __shared__ int off[NRELS + 1];
    __shared__ int toff[NRELS + 1];
    if (threadIdx.x == 0) {
        int a = 0, t = 0;
        for (int r = 0; r < NRELS; r++) {
            off[r] = a; toff[r] = t;
            a += counts[r];
            t += (counts[r] + BM - 1) / BM;
        }
        off[NRELS] = a; toff[NRELS] = t;
    }
    __syncthreads();
    if (threadIdx.x < NRELS) cursors[threadIdx.x] = off[threadIdx.x];
    for (int t = threadIdx.x; t < MAX_TILES; t += 256) {
        Tile tl; tl.rel = 0; tl.row0 = 0; tl.cnt = 0;
        for (int r = 0; r < NRELS; r++) {
            if (t >= toff[r] && t < toff[r + 1]) {
                int k = t - toff[r];
                tl.rel = r;
                tl.row0 = off[r] + k * BM;
                int rem = counts[r] - k * BM;
                tl.cnt = rem < BM ? rem : BM;
            }
        }
        tiles[t] = tl;
    }
}

// ---- bucket-fill: perm (relation-sorted) + dst/src CSR of positions ----
__global__ __launch_bounds__(256) void k_fill(const int* __restrict__ et,
                                              const int* __restrict__ src,
                                              const int* __restrict__ dst,
                                              int* cursors, int* perm,
                                              int* curf, int* curb,
                                              int* csrf, int* csrb) {
    __shared__ int lc[NRELS];
    __shared__ int lbase[NRELS];
    if (threadIdx.x < NRELS) lc[threadIdx.x] = 0;
    __syncthreads();
    int e = blockIdx.x * 256 + threadIdx.x;
    int r = -1, rank = 0;
    if (e < N_EDGES) {
        r = et[e];
        rank = atomicAdd(&lc[r], 1);
    }
    __syncthreads();
    if (threadIdx.x < NRELS && lc[threadIdx.x] > 0)
        lbase[threadIdx.x] = atomicAdd(&cursors[threadIdx.x], lc[threadIdx.x]);
    __syncthreads();
    if (e < N_EDGES) {
        int p = lbase[r] + rank;
        perm[p] = e;
        csrf[atomicAdd(&curf[dst[e]], 1)] = p;
        csrb[atomicAdd(&curb[src[e]], 1)] = p;
    }
}

// ---- self loop: out = 2*(feat @ loop_weight) + self_bias  (overwrites out) ----
__global__ __launch_bounds__(256) void k_self(const unsigned short* __restrict__ featb,
                                              const unsigned short* __restrict__ lwt,
                                              const float* __restrict__ sbias,
                                              float* __restrict__ out) {
    int m0 = blockIdx.x * BM;
    int wave = threadIdx.x >> 6, lane = threadIdx.x & 63;
    int nb = wave * 64, lr = lane & 15, lg = lane >> 4;
    f32x4 acc[4][4] = {};
    for (int k0 = 0; k0 < FEAT; k0 += 32) {
        int kk = k0 + lg * 8;
        bf16x8 a[4], b[4];
        for (int mi = 0; mi < 4; mi++) {
            int row = m0 + mi * 16 + lr;
            if (row >= N_NODES) row = N_NODES - 1;
            a[mi] = *(const bf16x8*)(featb + row * FEAT + kk);
        }
        for (int ni = 0; ni < 4; ni++) {
            int col = nb + ni * 16 + lr;
            b[ni] = *(const bf16x8*)(lwt + col * FEAT + kk);
        }
        for (int mi = 0; mi < 4; mi++)
            for (int ni = 0; ni < 4; ni++)
                acc[mi][ni] = __builtin_amdgcn_mfma_f32_16x16x32_bf16(a[mi], b[ni], acc[mi][ni], 0, 0, 0);
    }
    for (int mi = 0; mi < 4; mi++) {
        for (int j = 0; j < 4; j++) {
            int row = m0 + mi * 16 + lg * 4 + j;
            if (row < N_NODES) {
                for (int ni = 0; ni < 4; ni++) {
                    int col = nb + ni * 16 + lr;
                    out[row * FEAT + col] = 2.0f * acc[mi][ni][j] + sbias[col];
                }
            }
        }
    }
}

// ---- edge GEMM, write bf16 message rows at relation-sorted position p ----
__global__ __launch_bounds__(256) void k_msg(const unsigned short* __restrict__ featb,
                                             const unsigned short* __restrict__ wt,
                                             const int* __restrict__ gidx,
                                             const int* __restrict__ perm,
                                             const Tile* __restrict__ tiles,
                                             unsigned short* __restrict__ msg) {
    Tile tl = tiles[blockIdx.x];
    if (tl.cnt == 0) return;
    int wave = threadIdx.x >> 6, lane = threadIdx.x & 63;
    int nb = wave * 64, lr = lane & 15, lg = lane >> 4;
    const unsigned short* wr = wt + tl.rel * FEAT * FEAT;

    int anode[4];
    for (int mi = 0; mi < 4; mi++) {
        int row = mi * 16 + lr;
        int eid = (row < tl.cnt) ? perm[tl.row0 + row] : perm[tl.row0];
        anode[mi] = gidx[eid];
    }

    f32x4 acc[4][4] = {};
    for (int k0 = 0; k0 < FEAT; k0 += 32) {
        int kk = k0 + lg * 8;
        bf16x8 a[4], b[4];
        for (int mi = 0; mi < 4; mi++)
            a[mi] = *(const bf16x8*)(featb + anode[mi] * FEAT + kk);
        for (int ni = 0; ni < 4; ni++)
            b[ni] = *(const bf16x8*)(wr + (nb + ni * 16 + lr) * FEAT + kk);
        for (int mi = 0; mi < 4; mi++)
            for (int ni = 0; ni < 4; ni++)
                acc[mi][ni] = __builtin_amdgcn_mfma_f32_16x16x32_bf16(a[mi], b[ni], acc[mi][ni], 0, 0, 0);
    }

    for (int mi = 0; mi < 4; mi++) {
        for (int j = 0; j < 4; j++) {
            int row = mi * 16 + lg * 4 + j;
            if (row < tl.cnt) {
                int p = tl.row0 + row;
                unsigned short* mp = msg + (size_t)p * FEAT + nb + lr;
                for (int ni = 0; ni < 4; ni++)
                    mp[ni * 16] = f2bf(acc[mi][ni][j]);
            }
        }
    }
}

// ---- pull reduce: one wave per node; fwd + bwd; RMW out (self already there) ----
__global__ __launch_bounds__(256) void k_reduce(const unsigned short* __restrict__ msgf,
                                                const unsigned short* __restrict__ msgb,
                                                const int* __restrict__ csrf,
                                                const int* __restrict__ csrb,
                                                const int* __restrict__ offf,
                                                const int* __restrict__ offb,
                                                const float* __restrict__ normf,
                                                const float* __restrict__ normb,
                                                const float* __restrict__ biasf,
                                                const float* __restrict__ biasb,
                                                float* __restrict__ out) {
    int node = blockIdx.x * 4 + (threadIdx.x >> 6);
    if (node >= N_NODES) return;
    int lane = threadIdx.x & 63;

    float af0 = 0.f, af1 = 0.f, af2 = 0.f, af3 = 0.f;
    int b0 = offf[node], b1 = offf[node + 1];
    for (int s = b0; s < b1; ++s) {
        int p = csrf[s];
        ushort4 m = *(const ushort4*)(msgf + (size_t)p * FEAT + lane * 4);
        af0 += bf2f(m.x); af1 += bf2f(m.y); af2 += bf2f(m.z); af3 += bf2f(m.w);
    }
    float ab0 = 0.f, ab1 = 0.f, ab2 = 0.f, ab3 = 0.f;
    int c0 = offb[node], c1 = offb[node + 1];
    for (int s = c0; s < c1; ++s) {
        int p = csrb[s];
        ushort4 m = *(const ushort4*)(msgb + (size_t)p * FEAT + lane * 4);
        ab0 += bf2f(m.x); ab1 += bf2f(m.y); ab2 += bf2f(m.z); ab3 += bf2f(m.w);
    }
    float nf = normf[node], nbv = normb[node];
    float4 bf = *(const float4*)(biasf + lane * 4);
    float4 bb = *(const float4*)(biasb + lane * 4);
    float4 o = *(float4*)(out + (size_t)node * FEAT + lane * 4);
    o.x += nf * af0 + nbv * ab0 + (b1 > b0 ? bf.x : 0.f) + (c1 > c0 ? bb.x : 0.f);
    o.y += nf * af1 + nbv * ab1 + (b1 > b0 ? bf.y : 0.f) + (c1 > c0 ? bb.y : 0.f);
    o.z += nf * af2 + nbv * ab2 + (b1 > b0 ? bf.z : 0.f) + (c1 > c0 ? bb.z : 0.f);
    o.w += nf * af3 + nbv * ab3 + (b1 > b0 ? bf.w : 0.f) + (c1 > c0 ? bb.w : 0.f);
    *(float4*)(out + (size_t)node * FEAT + lane * 4) = o;
}

// ---- fallback: fused edge pass with atomic scatter (round-2 path) ----
__global__ __launch_bounds__(256) void k_edge(const unsigned short* __restrict__ featb,
                                              const unsigned short* __restrict__ wt,
                                              const float* __restrict__ bias,
                                              const float* __restrict__ normv,
                                              const int* __restrict__ gidx,
                                              const int* __restrict__ sidx,
                                              const int* __restrict__ perm,
                                              const Tile* __restrict__ tiles,
                                              float* __restrict__ out) {
    Tile tl = tiles[blockIdx.x];
    if (tl.cnt == 0) return;
    int wave = threadIdx.x >> 6, lane = threadIdx.x & 63;
    int nb = wave * 64, lr = lane & 15, lg = lane >> 4;
    const unsigned short* wr = wt + tl.rel * FEAT * FEAT;

    int anode[4];
    for (int mi = 0; mi < 4; mi++) {
        int row = mi * 16 + lr;
        int eid = (row < tl.cnt) ? perm[tl.row0 + row] : perm[tl.row0];
        anode[mi] = gidx[eid];
    }

    f32x4 acc[4][4] = {};
    for (int k0 = 0; k0 < FEAT; k0 += 32) {
        int kk = k0 + lg * 8;
        bf16x8 a[4], b[4];
        for (int mi = 0; mi < 4; mi++)
            a[mi] = *(const bf16x8*)(featb + anode[mi] * FEAT + kk);
        for (int ni = 0; ni < 4; ni++)
            b[ni] = *(const bf16x8*)(wr + (nb + ni * 16 + lr) * FEAT + kk);
        for (int mi = 0; mi < 4; mi++)
            for (int ni = 0; ni < 4; ni++)
                acc[mi][ni] = __builtin_amdgcn_mfma_f32_16x16x32_bf16(a[mi], b[ni], acc[mi][ni], 0, 0, 0);
    }

    float bv[4];
    for (int ni = 0; ni < 4; ni++) bv[ni] = bias[nb + ni * 16 + lr];

    for (int mi = 0; mi < 4; mi++) {
        for (int j = 0; j < 4; j++) {
            int row = mi * 16 + lg * 4 + j;
            if (row < tl.cnt) {
                int eid = perm[tl.row0 + row];
                int dn = sidx[eid];
                float nrm = normv[dn];
                float* op = out + dn * FEAT + nb + lr;
                for (int ni = 0; ni < 4; ni++)
                    atomicAdd(op + ni * 16, (acc[mi][ni][j] + bv[ni]) * nrm);
            }
        }
    }
}

extern "C" void kernel_launch(void* const* d_in, const int* in_sizes, int n_in,
                              void* d_out, int out_size, void* d_ws, size_t ws_size,
                              hipStream_t stream) {
    const float* feat  = (const float*)d_in[0];
    const float* Wf    = (const float*)d_in[1];
    const float* Wb    = (const float*)d_in[2];
    const float* lw    = (const float*)d_in[3];
    const float* fbias = (const float*)d_in[4];
    const float* bbias = (const float*)d_in[5];
    const float* sbias = (const float*)d_in[6];
    const int*   src   = (const int*)d_in[7];
    const int*   dst   = (const int*)d_in[8];
    const int*   et    = (const int*)d_in[9];
    float* out = (float*)d_out;

    char* ws = (char*)d_ws;
    size_t off = 0;
    auto alloc = [&](size_t bytes) { void* p = ws + off; off = (off + bytes + 255) & ~(size_t)255; return p; };

    int*   counts  = (int*)alloc(64);
    int*   cursors = (int*)alloc(64);
    int*   degd    = (int*)alloc(N_NODES * 4);
    int*   degs    = (int*)alloc(N_NODES * 4);
    size_t zero_bytes = off;                         // zero prefix: counts..degs
    int*   offf    = (int*)alloc((N_NODES + 1) * 4);
    int*   offb    = (int*)alloc((N_NODES + 1) * 4);
    int*   curf    = (int*)alloc(N_NODES * 4);
    int*   curb    = (int*)alloc(N_NODES * 4);
    float* normf   = (float*)alloc(N_NODES * 4);
    float* normb   = (float*)alloc(N_NODES * 4);
    int*   perm    = (int*)alloc(N_EDGES * 4);
    int*   csrf    = (int*)alloc(N_EDGES * 4);
    int*   csrb    = (int*)alloc(N_EDGES * 4);
    Tile*  tiles   = (Tile*)alloc(MAX_TILES * sizeof(Tile));
    unsigned short* featb = (unsigned short*)alloc((size_t)N_NODES * FEAT * 2);
    unsigned short* wft   = (unsigned short*)alloc((size_t)NRELS * FEAT * FEAT * 2);
    unsigned short* wbt   = (unsigned short*)alloc((size_t)NRELS * FEAT * FEAT * 2);
    unsigned short* lwt   = (unsigned short*)alloc((size_t)FEAT * FEAT * 2);
    size_t small_end = off;
    unsigned short* msgf  = (unsigned short*)alloc((size_t)N_EDGES * FEAT * 2);
    unsigned short* msgb  = (unsigned short*)alloc((size_t)N_EDGES * FEAT * 2);
    bool two_phase = (off <= ws_size);
    (void)small_end;

    hipMemsetAsync(d_ws, 0, zero_bytes, stream);

    // prep conversions
    {
        int n4 = N_NODES * FEAT / 4;
        k_f2bf4<<<(n4 + 255) / 256, 256, 0, stream>>>((const float4*)feat, (ushort4*)featb, n4);
        int tw = NRELS * FEAT * FEAT;
        k_wt<<<(tw + 255) / 256, 256, 0, stream>>>(Wf, wft, tw);
        k_wt<<<(tw + 255) / 256, 256, 0, stream>>>(Wb, wbt, tw);
        int tl = FEAT * FEAT;
        k_wt<<<(tl + 255) / 256, 256, 0, stream>>>(lw, lwt, tl);
    }

    // counts, scan (offsets + cursors + norms), tile descriptors, bucket/CSR fill
    k_count<<<(N_EDGES + 255) / 256, 256, 0, stream>>>(src, dst, et, degd, degs, counts);
    k_scan<<<1, 1024, 0, stream>>>(degd, degs, offf, offb, curf, curb, normf, normb);
    k_desc<<<1, 256, 0, stream>>>(counts, cursors, tiles);
    k_fill<<<(N_EDGES + 255) / 256, 256, 0, stream>>>(et, src, dst, cursors, perm, curf, curb, csrf, csrb);

    // self loop writes out
    k_self<<<(N_NODES + BM - 1) / BM, 256, 0, stream>>>(featb, lwt, sbias, out);

    if (two_phase) {
        // forward messages: gather feat[src]; backward: gather feat[dst]
        k_msg<<<MAX_TILES, 256, 0, stream>>>(featb, wft, src, perm, tiles, msgf);
        k_msg<<<MAX_TILES, 256, 0, stream>>>(featb, wbt, dst, perm, tiles, msgb);
        // pull-reduce both passes, non-atomic RMW on out
        k_reduce<<<(N_NODES + 3) / 4, 256, 0, stream>>>(msgf, msgb, csrf, csrb, offf, offb,
                                                        normf, normb, fbias, bbias, out);
    } else {
        // fallback: atomic scatter path
        k_edge<<<MAX_TILES, 256, 0, stream>>>(featb, wft, fbias, normf, src, dst, perm, tiles, out);
        k_edge<<<MAX_TILES, 256, 0, stream>>>(featb, wbt, bbias, normb, dst, src, perm, tiles, out);
    }
}

// Round 4
// 321.059 us; speedup vs baseline: 4.0651x; 1.0546x over previous
//
#include <hip/hip_runtime.h>
#include <hip/hip_bf16.h>
#include <stdint.h>

#define N_NODES 10000
#define N_EDGES 160000
#define FEAT    256
#define NRELS   16
#define BM      64
#define NCHUNK  32          // 16 rels x {fwd,bwd}; proj row chunk = rd in [0,32)

typedef __attribute__((ext_vector_type(8))) short bf16x8;
typedef __attribute__((ext_vector_type(4))) float f32x4;

__device__ __forceinline__ unsigned short f2bf(float f) {
    union { float f; unsigned u; } v; v.f = f;
    unsigned u = v.u;
    u += 0x7FFFu + ((u >> 16) & 1u);   // round-to-nearest-even
    return (unsigned short)(u >> 16);
}
__device__ __forceinline__ float bf2f(unsigned short u) {
    union { unsigned u; float f; } v; v.u = ((unsigned)u) << 16;
    return v.f;
}

// ---- prep: fp32 -> bf16 (vectorized) ----
__global__ __launch_bounds__(256) void k_f2bf4(const float4* __restrict__ src,
                                               ushort4* __restrict__ dst, int n4) {
    int i = blockIdx.x * 256 + threadIdx.x;
    if (i < n4) {
        float4 v = src[i];
        ushort4 r;
        r.x = f2bf(v.x); r.y = f2bf(v.y); r.z = f2bf(v.z); r.w = f2bf(v.w);
        dst[i] = r;
    }
}

// ---- prep: W [R][I][O] fp32 -> wall[((r*2+dir)*256+o)][i] bf16 ----
__global__ __launch_bounds__(256) void k_wt(const float* __restrict__ w,
                                            unsigned short* __restrict__ wall,
                                            int dir, int total) {
    int idx = blockIdx.x * 256 + threadIdx.x;
    if (idx < total) {
        int i = idx & 255;
        int o = (idx >> 8) & 255;
        int r = idx >> 16;
        wall[(((size_t)(r * 2 + dir) * 256 + o) << 8) + i] = f2bf(w[((r << 8) + i) * 256 + o]);
    }
}

// ---- degrees (int, low contention) ----
__global__ __launch_bounds__(256) void k_count(const int* __restrict__ src,
                                               const int* __restrict__ dst,
                                               int* degd, int* degs) {
    int e = blockIdx.x * 256 + threadIdx.x;
    if (e < N_EDGES) {
        atomicAdd(&degd[dst[e]], 1);
        atomicAdd(&degs[src[e]], 1);
    }
}

// ---- single-block exclusive scan of both degree arrays; offsets + cursors + norms ----
__global__ __launch_bounds__(1024) void k_scan(const int* __restrict__ degd,
                                               const int* __restrict__ degs,
                                               int* offf, int* offb,
                                               int* curf, int* curb,
                                               float* normf, float* normb) {
    __shared__ int sf[1024], sb[1024];
    int t = threadIdx.x;
    const int CH = (N_NODES + 1023) / 1024;   // 10
    int base = t * CH;
    int sumf = 0, sumb = 0;
    for (int i = 0; i < CH; i++) {
        int n = base + i;
        if (n < N_NODES) { sumf += degd[n]; sumb += degs[n]; }
    }
    sf[t] = sumf; sb[t] = sumb;
    __syncthreads();
    for (int d = 1; d < 1024; d <<= 1) {
        int vf = (t >= d) ? sf[t - d] : 0;
        int vb = (t >= d) ? sb[t - d] : 0;
        __syncthreads();
        sf[t] += vf; sb[t] += vb;
        __syncthreads();
    }
    int runf = t ? sf[t - 1] : 0;
    int runb = t ? sb[t - 1] : 0;
    for (int i = 0; i < CH; i++) {
        int n = base + i;
        if (n < N_NODES) {
            int df = degd[n], db = degs[n];
            offf[n] = runf; offb[n] = runb;
            curf[n] = runf; curb[n] = runb;
            normf[n] = df > 0 ? 1.f / (float)df : 0.f;
            normb[n] = db > 0 ? 1.f / (float)db : 0.f;
            runf += df; runb += db;
        }
    }
    if (t == 1023) { offf[N_NODES] = runf; offb[N_NODES] = runb; }
}

// ---- CSR fill: store precomputed proj chunk index (node*32 + et*2 + dir) ----
__global__ __launch_bounds__(256) void k_fill(const int* __restrict__ et,
                                              const int* __restrict__ src,
                                              const int* __restrict__ dst,
                                              int* curf, int* curb,
                                              int* csrf, int* csrb) {
    int e = blockIdx.x * 256 + threadIdx.x;
    if (e < N_EDGES) {
        int s = src[e], d = dst[e], r = et[e];
        csrf[atomicAdd(&curf[d], 1)] = s * NCHUNK + r * 2;       // fwd: gather feat[src]
        csrb[atomicAdd(&curb[s], 1)] = d * NCHUNK + r * 2 + 1;   // bwd: gather feat[dst]
    }
}

// ---- self loop: out = 2*(feat @ loop_weight) + self_bias  (overwrites out) ----
__global__ __launch_bounds__(256) void k_self(const unsigned short* __restrict__ featb,
                                              const unsigned short* __restrict__ lwt,
                                              const float* __restrict__ sbias,
                                              float* __restrict__ out) {
    int m0 = blockIdx.x * BM;
    int wave = threadIdx.x >> 6, lane = threadIdx.x & 63;
    int nb = wave * 64, lr = lane & 15, lg = lane >> 4;
    f32x4 acc[4][4] = {};
    for (int k0 = 0; k0 < FEAT; k0 += 32) {
        int kk = k0 + lg * 8;
        bf16x8 a[4], b[4];
        for (int mi = 0; mi < 4; mi++) {
            int row = m0 + mi * 16 + lr;
            if (row >= N_NODES) row = N_NODES - 1;
            a[mi] = *(const bf16x8*)(featb + row * FEAT + kk);
        }
        for (int ni = 0; ni < 4; ni++) {
            int col = nb + ni * 16 + lr;
            b[ni] = *(const bf16x8*)(lwt + col * FEAT + kk);
        }
        for (int mi = 0; mi < 4; mi++)
            for (int ni = 0; ni < 4; ni++)
                acc[mi][ni] = __builtin_amdgcn_mfma_f32_16x16x32_bf16(a[mi], b[ni], acc[mi][ni], 0, 0, 0);
    }
    for (int mi = 0; mi < 4; mi++) {
        for (int j = 0; j < 4; j++) {
            int row = m0 + mi * 16 + lg * 4 + j;
            if (row < N_NODES) {
                for (int ni = 0; ni < 4; ni++) {
                    int col = nb + ni * 16 + lr;
                    out[row * FEAT + col] = 2.0f * acc[mi][ni][j] + sbias[col];
                }
            }
        }
    }
}

// ---- dense projection: proj[n][rd][256] = feat @ W_rd  (all rels, both dirs) ----
__global__ __launch_bounds__(256) void k_proj(const unsigned short* __restrict__ featb,
                                              const unsigned short* __restrict__ wall,
                                              unsigned short* __restrict__ proj) {
    int m0 = blockIdx.x * BM;
    int rd = blockIdx.y;                    // 0..31
    int wave = threadIdx.x >> 6, lane = threadIdx.x & 63;
    int nb = wave * 64, lr = lane & 15, lg = lane >> 4;
    const unsigned short* wr = wall + (size_t)rd * 256 * FEAT;

    f32x4 acc[4][4] = {};
#pragma unroll 2
    for (int k0 = 0; k0 < FEAT; k0 += 32) {
        int kk = k0 + lg * 8;
        bf16x8 a[4], b[4];
        for (int mi = 0; mi < 4; mi++) {
            int row = m0 + mi * 16 + lr;
            if (row >= N_NODES) row = N_NODES - 1;   // masked at store
            a[mi] = *(const bf16x8*)(featb + row * FEAT + kk);
        }
        for (int ni = 0; ni < 4; ni++)
            b[ni] = *(const bf16x8*)(wr + (nb + ni * 16 + lr) * FEAT + kk);
        for (int mi = 0; mi < 4; mi++)
            for (int ni = 0; ni < 4; ni++)
                acc[mi][ni] = __builtin_amdgcn_mfma_f32_16x16x32_bf16(a[mi], b[ni], acc[mi][ni], 0, 0, 0);
    }
    for (int mi = 0; mi < 4; mi++) {
        for (int j = 0; j < 4; j++) {
            int row = m0 + mi * 16 + lg * 4 + j;
            if (row < N_NODES) {
                unsigned short* pp = proj + ((size_t)row * NCHUNK + rd) * FEAT + nb + lr;
                for (int ni = 0; ni < 4; ni++)
                    pp[ni * 16] = f2bf(acc[mi][ni][j]);
            }
        }
    }
}

// ---- pull reduce: one wave per node; fwd + bwd; RMW out (self already there) ----
__global__ __launch_bounds__(256) void k_reduce(const unsigned short* __restrict__ proj,
                                                const int* __restrict__ csrf,
                                                const int* __restrict__ csrb,
                                                const int* __restrict__ offf,
                                                const int* __restrict__ offb,
                                                const float* __restrict__ normf,
                                                const float* __restrict__ normb,
                                                const float* __restrict__ biasf,
                                                const float* __restrict__ biasb,
                                                float* __restrict__ out) {
    int node = blockIdx.x * 4 + (threadIdx.x >> 6);
    if (node >= N_NODES) return;
    int lane = threadIdx.x & 63;

    float af0 = 0.f, af1 = 0.f, af2 = 0.f, af3 = 0.f;
    int b0 = offf[node], b1 = offf[node + 1];
    for (int s = b0; s < b1; ++s) {
        int c = csrf[s];
        ushort4 m = *(const ushort4*)(proj + (size_t)c * FEAT + lane * 4);
        af0 += bf2f(m.x); af1 += bf2f(m.y); af2 += bf2f(m.z); af3 += bf2f(m.w);
    }
    float ab0 = 0.f, ab1 = 0.f, ab2 = 0.f, ab3 = 0.f;
    int c0 = offb[node], c1 = offb[node + 1];
    for (int s = c0; s < c1; ++s) {
        int c = csrb[s];
        ushort4 m = *(const ushort4*)(proj + (size_t)c * FEAT + lane * 4);
        ab0 += bf2f(m.x); ab1 += bf2f(m.y); ab2 += bf2f(m.z); ab3 += bf2f(m.w);
    }
    float nf = normf[node], nbv = normb[node];
    float4 bf = *(const float4*)(biasf + lane * 4);
    float4 bb = *(const float4*)(biasb + lane * 4);
    float4 o = *(float4*)(out + (size_t)node * FEAT + lane * 4);
    o.x += nf * af0 + nbv * ab0 + (b1 > b0 ? bf.x : 0.f) + (c1 > c0 ? bb.x : 0.f);
    o.y += nf * af1 + nbv * ab1 + (b1 > b0 ? bf.y : 0.f) + (c1 > c0 ? bb.y : 0.f);
    o.z += nf * af2 + nbv * ab2 + (b1 > b0 ? bf.z : 0.f) + (c1 > c0 ? bb.z : 0.f);
    o.w += nf * af3 + nbv * ab3 + (b1 > b0 ? bf.w : 0.f) + (c1 > c0 ? bb.w : 0.f);
    *(float4*)(out + (size_t)node * FEAT + lane * 4) = o;
}

extern "C" void kernel_launch(void* const* d_in, const int* in_sizes, int n_in,
                              void* d_out, int out_size, void* d_ws, size_t ws_size,
                              hipStream_t stream) {
    const float* feat  = (const float*)d_in[0];
    const float* Wf    = (const float*)d_in[1];
    const float* Wb    = (const float*)d_in[2];
    const float* lw    = (const float*)d_in[3];
    const float* fbias = (const float*)d_in[4];
    const float* bbias = (const float*)d_in[5];
    const float* sbias = (const float*)d_in[6];
    const int*   src   = (const int*)d_in[7];
    const int*   dst   = (const int*)d_in[8];
    const int*   et    = (const int*)d_in[9];
    float* out = (float*)d_out;

    char* ws = (char*)d_ws;
    size_t off = 0;
    auto alloc = [&](size_t bytes) { void* p = ws + off; off = (off + bytes + 255) & ~(size_t)255; return p; };

    int*   degd  = (int*)alloc(N_NODES * 4);
    int*   degs  = (int*)alloc(N_NODES * 4);
    size_t zero_bytes = off;                         // zero prefix: degd, degs
    int*   offf  = (int*)alloc((N_NODES + 1) * 4);
    int*   offb  = (int*)alloc((N_NODES + 1) * 4);
    int*   curf  = (int*)alloc(N_NODES * 4);
    int*   curb  = (int*)alloc(N_NODES * 4);
    float* normf = (float*)alloc(N_NODES * 4);
    float* normb = (float*)alloc(N_NODES * 4);
    int*   csrf  = (int*)alloc(N_EDGES * 4);
    int*   csrb  = (int*)alloc(N_EDGES * 4);
    unsigned short* featb = (unsigned short*)alloc((size_t)N_NODES * FEAT * 2);
    unsigned short* wall  = (unsigned short*)alloc((size_t)NCHUNK * 256 * FEAT * 2);   // 4 MB
    unsigned short* lwt   = (unsigned short*)alloc((size_t)FEAT * FEAT * 2);
    unsigned short* proj  = (unsigned short*)alloc((size_t)N_NODES * NCHUNK * FEAT * 2); // 164 MB
    (void)ws_size;

    hipMemsetAsync(d_ws, 0, zero_bytes, stream);

    // prep conversions
    {
        int n4 = N_NODES * FEAT / 4;
        k_f2bf4<<<(n4 + 255) / 256, 256, 0, stream>>>((const float4*)feat, (ushort4*)featb, n4);
        int tw = NRELS * FEAT * FEAT;
        k_wt<<<(tw + 255) / 256, 256, 0, stream>>>(Wf, wall, 0, tw);
        k_wt<<<(tw + 255) / 256, 256, 0, stream>>>(Wb, wall, 1, tw);
        int tl = FEAT * FEAT;
        k_wt<<<(tl + 255) / 256, 256, 0, stream>>>(lw, lwt, 0, tl);
    }

    // degrees, scan (offsets + cursors + norms), CSR fill
    k_count<<<(N_EDGES + 255) / 256, 256, 0, stream>>>(src, dst, degd, degs);
    k_scan<<<1, 1024, 0, stream>>>(degd, degs, offf, offb, curf, curb, normf, normb);
    k_fill<<<(N_EDGES + 255) / 256, 256, 0, stream>>>(et, src, dst, curf, curb, csrf, csrb);

    // self loop writes out
    k_self<<<(N_NODES + BM - 1) / BM, 256, 0, stream>>>(featb, lwt, sbias, out);

    // dense projection for all 16 relations x {fwd,bwd}
    {
        dim3 grid((N_NODES + BM - 1) / BM, NCHUNK);
        k_proj<<<grid, 256, 0, stream>>>(featb, wall, proj);
    }

    // pull-reduce both passes, non-atomic RMW on out
    k_reduce<<<(N_NODES + 3) / 4, 256, 0, stream>>>(proj, csrf, csrb, offf, offb,
                                                    normf, normb, fbias, bbias, out);
}

// Round 5
// 242.306 us; speedup vs baseline: 5.3863x; 1.3250x over previous
//
#include <hip/hip_runtime.h>
#include <hip/hip_bf16.h>
#include <stdint.h>

#define N_NODES 10000
#define N_EDGES 160000
#define FEAT    256
#define NRELS   16
#define BM      64
#define NCHUNK  32          // 16 rels x {fwd,bwd}; proj row chunk = rd in [0,32)
#define KBYTES  512         // one A row = 256 bf16 = 512 B

typedef __attribute__((ext_vector_type(8))) short bf16x8;
typedef __attribute__((ext_vector_type(4))) float f32x4;

__device__ __forceinline__ unsigned short f2bf(float f) {
    union { float f; unsigned u; } v; v.f = f;
    unsigned u = v.u;
    u += 0x7FFFu + ((u >> 16) & 1u);   // round-to-nearest-even
    return (unsigned short)(u >> 16);
}
__device__ __forceinline__ float bf2f(unsigned short u) {
    union { unsigned u; float f; } v; v.u = ((unsigned)u) << 16;
    return v.f;
}

// ---- prep: fp32 -> bf16 (vectorized) ----
__global__ __launch_bounds__(256) void k_f2bf4(const float4* __restrict__ src,
                                               ushort4* __restrict__ dst, int n4) {
    int i = blockIdx.x * 256 + threadIdx.x;
    if (i < n4) {
        float4 v = src[i];
        ushort4 r;
        r.x = f2bf(v.x); r.y = f2bf(v.y); r.z = f2bf(v.z); r.w = f2bf(v.w);
        dst[i] = r;
    }
}

// ---- prep: tiled transpose W [256][256] fp32 (per rel) -> wall[(r*2+dir)*256+o][i] bf16 ----
// grid (4, 4, nrels); block 256. Coalesced reads (o contiguous) and writes (i contiguous).
__global__ __launch_bounds__(256) void k_wt(const float* __restrict__ w,
                                            unsigned short* __restrict__ wall,
                                            int dir) {
    __shared__ float tile[64][65];
    int r  = blockIdx.z;
    int i0 = blockIdx.x * 64, o0 = blockIdx.y * 64;
    int t = threadIdx.x;
    int c = t & 63, q = t >> 6;          // c: fast index, q: 0..3
#pragma unroll
    for (int it = 0; it < 16; it++) {
        int i = it * 4 + q;
        tile[i][c] = w[((size_t)r * 256 + i0 + i) * 256 + o0 + c];
    }
    __syncthreads();
#pragma unroll
    for (int it = 0; it < 16; it++) {
        int o = it * 4 + q;
        wall[((size_t)(r * 2 + dir) * 256 + o0 + o) * 256 + i0 + c] = f2bf(tile[c][o]);
    }
}

// ---- degrees (int, low contention) ----
__global__ __launch_bounds__(256) void k_count(const int* __restrict__ src,
                                               const int* __restrict__ dst,
                                               int* degd, int* degs) {
    int e = blockIdx.x * 256 + threadIdx.x;
    if (e < N_EDGES) {
        atomicAdd(&degd[dst[e]], 1);
        atomicAdd(&degs[src[e]], 1);
    }
}

// ---- single-block exclusive scan of both degree arrays; offsets + cursors + norms ----
__global__ __launch_bounds__(1024) void k_scan(const int* __restrict__ degd,
                                               const int* __restrict__ degs,
                                               int* offf, int* offb,
                                               int* curf, int* curb,
                                               float* normf, float* normb) {
    __shared__ int sf[1024], sb[1024];
    int t = threadIdx.x;
    const int CH = (N_NODES + 1023) / 1024;   // 10
    int base = t * CH;
    int sumf = 0, sumb = 0;
    for (int i = 0; i < CH; i++) {
        int n = base + i;
        if (n < N_NODES) { sumf += degd[n]; sumb += degs[n]; }
    }
    sf[t] = sumf; sb[t] = sumb;
    __syncthreads();
    for (int d = 1; d < 1024; d <<= 1) {
        int vf = (t >= d) ? sf[t - d] : 0;
        int vb = (t >= d) ? sb[t - d] : 0;
        __syncthreads();
        sf[t] += vf; sb[t] += vb;
        __syncthreads();
    }
    int runf = t ? sf[t - 1] : 0;
    int runb = t ? sb[t - 1] : 0;
    for (int i = 0; i < CH; i++) {
        int n = base + i;
        if (n < N_NODES) {
            int df = degd[n], db = degs[n];
            offf[n] = runf; offb[n] = runb;
            curf[n] = runf; curb[n] = runb;
            normf[n] = df > 0 ? 1.f / (float)df : 0.f;
            normb[n] = db > 0 ? 1.f / (float)db : 0.f;
            runf += df; runb += db;
        }
    }
    if (t == 1023) { offf[N_NODES] = runf; offb[N_NODES] = runb; }
}

// ---- CSR fill: store precomputed proj chunk index (node*32 + et*2 + dir) ----
__global__ __launch_bounds__(256) void k_fill(const int* __restrict__ et,
                                              const int* __restrict__ src,
                                              const int* __restrict__ dst,
                                              int* curf, int* curb,
                                              int* csrf, int* csrb) {
    int e = blockIdx.x * 256 + threadIdx.x;
    if (e < N_EDGES) {
        int s = src[e], d = dst[e], r = et[e];
        csrf[atomicAdd(&curf[d], 1)] = s * NCHUNK + r * 2;       // fwd: gather feat[src]
        csrb[atomicAdd(&curb[s], 1)] = d * NCHUNK + r * 2 + 1;   // bwd: gather feat[dst]
    }
}

// ---- self loop: out = 2*(feat @ loop_weight) + self_bias  (overwrites out) ----
__global__ __launch_bounds__(256) void k_self(const unsigned short* __restrict__ featb,
                                              const unsigned short* __restrict__ lwt,
                                              const float* __restrict__ sbias,
                                              float* __restrict__ out) {
    int m0 = blockIdx.x * BM;
    int wave = threadIdx.x >> 6, lane = threadIdx.x & 63;
    int nb = wave * 64, lr = lane & 15, lg = lane >> 4;
    f32x4 acc[4][4] = {};
    for (int k0 = 0; k0 < FEAT; k0 += 32) {
        int kk = k0 + lg * 8;
        bf16x8 a[4], b[4];
        for (int mi = 0; mi < 4; mi++) {
            int row = m0 + mi * 16 + lr;
            if (row >= N_NODES) row = N_NODES - 1;
            a[mi] = *(const bf16x8*)(featb + row * FEAT + kk);
        }
        for (int ni = 0; ni < 4; ni++) {
            int col = nb + ni * 16 + lr;
            b[ni] = *(const bf16x8*)(lwt + col * FEAT + kk);
        }
        for (int mi = 0; mi < 4; mi++)
            for (int ni = 0; ni < 4; ni++)
                acc[mi][ni] = __builtin_amdgcn_mfma_f32_16x16x32_bf16(a[mi], b[ni], acc[mi][ni], 0, 0, 0);
    }
    for (int mi = 0; mi < 4; mi++) {
        for (int j = 0; j < 4; j++) {
            int row = m0 + mi * 16 + lg * 4 + j;
            if (row < N_NODES) {
                for (int ni = 0; ni < 4; ni++) {
                    int col = nb + ni * 16 + lr;
                    out[row * FEAT + col] = 2.0f * acc[mi][ni][j] + sbias[col];
                }
            }
        }
    }
}

// ---- dense projection: proj[n][rd][256] = feat @ W_rd ----
// LDS-staged A (XOR-swizzled), coalesced LDS-staged bf16 stores.
// grid (NCHUNK, nrow_tiles): x=rd so each XCD keeps its rd%8 weight set hot in L2.
__global__ __launch_bounds__(256) void k_proj(const unsigned short* __restrict__ featb,
                                              const unsigned short* __restrict__ wall,
                                              unsigned short* __restrict__ proj) {
    __shared__ __align__(16) char lds[BM * KBYTES];   // 32 KB: A tile, reused for out-stage
    int rd = blockIdx.x;
    int m0 = blockIdx.y * BM;
    int t = threadIdx.x;
    int wave = t >> 6, lane = t & 63;
    int nb = wave * 64, lr = lane & 15, lg = lane >> 4;
    const unsigned short* wr = wall + (size_t)rd * 256 * FEAT;

    // stage A tile [64][512B], swizzled: byte = row*512 + (kb ^ ((row&7)<<4))
    {
        int rl = t >> 5;                 // 0..7
        int kb = (t & 31) << 4;          // 0..496, 16B chunks
#pragma unroll
        for (int it = 0; it < 8; it++) {
            int row = it * 8 + rl;
            int gr = m0 + row; if (gr > N_NODES - 1) gr = N_NODES - 1;
            bf16x8 v = *(const bf16x8*)(featb + gr * FEAT + (kb >> 1));
            *(bf16x8*)(lds + row * KBYTES + (kb ^ ((row & 7) << 4))) = v;
        }
    }
    __syncthreads();

    f32x4 acc[4][4] = {};
#pragma unroll 2
    for (int k0 = 0; k0 < FEAT; k0 += 32) {
        int kb = (k0 + lg * 8) * 2;
        bf16x8 a[4], b[4];
        for (int ni = 0; ni < 4; ni++)
            b[ni] = *(const bf16x8*)(wr + (nb + ni * 16 + lr) * FEAT + k0 + lg * 8);
        for (int mi = 0; mi < 4; mi++) {
            int row = mi * 16 + lr;
            a[mi] = *(const bf16x8*)(lds + row * KBYTES + (kb ^ ((row & 7) << 4)));
        }
        for (int mi = 0; mi < 4; mi++)
            for (int ni = 0; ni < 4; ni++)
                acc[mi][ni] = __builtin_amdgcn_mfma_f32_16x16x32_bf16(a[mi], b[ni], acc[mi][ni], 0, 0, 0);
    }
    __syncthreads();

    // out-stage: bf16 results into LDS [64][256] linear
    for (int mi = 0; mi < 4; mi++) {
#pragma unroll
        for (int j = 0; j < 4; j++) {
            int row = mi * 16 + lg * 4 + j;
            for (int ni = 0; ni < 4; ni++)
                *(unsigned short*)(lds + row * KBYTES + (nb + ni * 16 + lr) * 2) =
                    f2bf(acc[mi][ni][j]);
        }
    }
    __syncthreads();

    // coalesced global write: 16B/lane, 512B bursts per row
    {
        int rl = t >> 5;
        int kb = (t & 31) << 4;
#pragma unroll
        for (int it = 0; it < 8; it++) {
            int row = it * 8 + rl;
            int gr = m0 + row;
            if (gr < N_NODES)
                *(bf16x8*)(proj + ((size_t)gr * NCHUNK + rd) * FEAT + (kb >> 1)) =
                    *(const bf16x8*)(lds + row * KBYTES + kb);
        }
    }
}

// ---- pull reduce: one wave per node; fwd + bwd; RMW out (self already there) ----
__global__ __launch_bounds__(256) void k_reduce(const unsigned short* __restrict__ proj,
                                                const int* __restrict__ csrf,
                                                const int* __restrict__ csrb,
                                                const int* __restrict__ offf,
                                                const int* __restrict__ offb,
                                                const float* __restrict__ normf,
                                                const float* __restrict__ normb,
                                                const float* __restrict__ biasf,
                                                const float* __restrict__ biasb,
                                                float* __restrict__ out) {
    int node = blockIdx.x * 4 + (threadIdx.x >> 6);
    if (node >= N_NODES) return;
    int lane = threadIdx.x & 63;

    float af0 = 0.f, af1 = 0.f, af2 = 0.f, af3 = 0.f;
    int b0 = offf[node], b1 = offf[node + 1];
    for (int s = b0; s < b1; ++s) {
        int c = csrf[s];
        ushort4 m = *(const ushort4*)(proj + (size_t)c * FEAT + lane * 4);
        af0 += bf2f(m.x); af1 += bf2f(m.y); af2 += bf2f(m.z); af3 += bf2f(m.w);
    }
    float ab0 = 0.f, ab1 = 0.f, ab2 = 0.f, ab3 = 0.f;
    int c0 = offb[node], c1 = offb[node + 1];
    for (int s = c0; s < c1; ++s) {
        int c = csrb[s];
        ushort4 m = *(const ushort4*)(proj + (size_t)c * FEAT + lane * 4);
        ab0 += bf2f(m.x); ab1 += bf2f(m.y); ab2 += bf2f(m.z); ab3 += bf2f(m.w);
    }
    float nf = normf[node], nbv = normb[node];
    float4 bf = *(const float4*)(biasf + lane * 4);
    float4 bb = *(const float4*)(biasb + lane * 4);
    float4 o = *(float4*)(out + (size_t)node * FEAT + lane * 4);
    o.x += nf * af0 + nbv * ab0 + (b1 > b0 ? bf.x : 0.f) + (c1 > c0 ? bb.x : 0.f);
    o.y += nf * af1 + nbv * ab1 + (b1 > b0 ? bf.y : 0.f) + (c1 > c0 ? bb.y : 0.f);
    o.z += nf * af2 + nbv * ab2 + (b1 > b0 ? bf.z : 0.f) + (c1 > c0 ? bb.z : 0.f);
    o.w += nf * af3 + nbv * ab3 + (b1 > b0 ? bf.w : 0.f) + (c1 > c0 ? bb.w : 0.f);
    *(float4*)(out + (size_t)node * FEAT + lane * 4) = o;
}

extern "C" void kernel_launch(void* const* d_in, const int* in_sizes, int n_in,
                              void* d_out, int out_size, void* d_ws, size_t ws_size,
                              hipStream_t stream) {
    const float* feat  = (const float*)d_in[0];
    const float* Wf    = (const float*)d_in[1];
    const float* Wb    = (const float*)d_in[2];
    const float* lw    = (const float*)d_in[3];
    const float* fbias = (const float*)d_in[4];
    const float* bbias = (const float*)d_in[5];
    const float* sbias = (const float*)d_in[6];
    const int*   src   = (const int*)d_in[7];
    const int*   dst   = (const int*)d_in[8];
    const int*   et    = (const int*)d_in[9];
    float* out = (float*)d_out;

    char* ws = (char*)d_ws;
    size_t off = 0;
    auto alloc = [&](size_t bytes) { void* p = ws + off; off = (off + bytes + 255) & ~(size_t)255; return p; };

    int*   degd  = (int*)alloc(N_NODES * 4);
    int*   degs  = (int*)alloc(N_NODES * 4);
    size_t zero_bytes = off;                         // zero prefix: degd, degs
    int*   offf  = (int*)alloc((N_NODES + 1) * 4);
    int*   offb  = (int*)alloc((N_NODES + 1) * 4);
    int*   curf  = (int*)alloc(N_NODES * 4);
    int*   curb  = (int*)alloc(N_NODES * 4);
    float* normf = (float*)alloc(N_NODES * 4);
    float* normb = (float*)alloc(N_NODES * 4);
    int*   csrf  = (int*)alloc(N_EDGES * 4);
    int*   csrb  = (int*)alloc(N_EDGES * 4);
    unsigned short* featb = (unsigned short*)alloc((size_t)N_NODES * FEAT * 2);
    unsigned short* wall  = (unsigned short*)alloc((size_t)NCHUNK * 256 * FEAT * 2);   // 4 MB
    unsigned short* lwt   = (unsigned short*)alloc((size_t)FEAT * FEAT * 2);
    unsigned short* proj  = (unsigned short*)alloc((size_t)N_NODES * NCHUNK * FEAT * 2); // 164 MB
    (void)ws_size;

    hipMemsetAsync(d_ws, 0, zero_bytes, stream);

    // prep conversions
    {
        int n4 = N_NODES * FEAT / 4;
        k_f2bf4<<<(n4 + 255) / 256, 256, 0, stream>>>((const float4*)feat, (ushort4*)featb, n4);
        dim3 gw(4, 4, NRELS);
        k_wt<<<gw, 256, 0, stream>>>(Wf, wall, 0);
        k_wt<<<gw, 256, 0, stream>>>(Wb, wall, 1);
        dim3 gl(4, 4, 1);
        k_wt<<<gl, 256, 0, stream>>>(lw, lwt, 0);
    }

    // degrees, scan (offsets + cursors + norms), CSR fill
    k_count<<<(N_EDGES + 255) / 256, 256, 0, stream>>>(src, dst, degd, degs);
    k_scan<<<1, 1024, 0, stream>>>(degd, degs, offf, offb, curf, curb, normf, normb);
    k_fill<<<(N_EDGES + 255) / 256, 256, 0, stream>>>(et, src, dst, curf, curb, csrf, csrb);

    // self loop writes out
    k_self<<<(N_NODES + BM - 1) / BM, 256, 0, stream>>>(featb, lwt, sbias, out);

    // dense projection for all 16 relations x {fwd,bwd}
    {
        dim3 grid(NCHUNK, (N_NODES + BM - 1) / BM);
        k_proj<<<grid, 256, 0, stream>>>(featb, wall, proj);
    }

    // pull-reduce both passes, non-atomic RMW on out
    k_reduce<<<(N_NODES + 3) / 4, 256, 0, stream>>>(proj, csrf, csrb, offf, offb,
                                                    normf, normb, fbias, bbias, out);
}